// Round 1
// baseline (22024.214 us; speedup 1.0000x reference)
//
#include <hip/hip_runtime.h>

// STN-Euler LSTM scan. B=64, T=4096, IN=64, H=512, K=0.5.
// 256 persistent WGs: 4 batch-groups x 64 unit-slices. Per-step h exchange via
// LLC: publishers store 256B payload rows + per-WG generation flag (no RMW
// counter); readers poll flags wave-parallel and load MFMA A-fragments
// DIRECTLY from the payload into registers (no LDS staging). W fragments and
// bias live in registers. One __syncthreads per timestep.

#define Bsz  64
#define Tlen 4096
#define INs  64
#define Hs   512
#define NG   4            // batch groups
#define GB   16           // batches per group (MFMA M=16)
#define RR   32           // gate rows per WG (8 units x 4 gates)

typedef float  floatx4 __attribute__((ext_vector_type(4)));
typedef float  floatx2 __attribute__((ext_vector_type(2)));
typedef short  short8  __attribute__((ext_vector_type(8)));
typedef unsigned long long u64;

__device__ __forceinline__ unsigned short f2bf(float x) {
    unsigned u = __float_as_uint(x);
    u += 0x7fffu + ((u >> 16) & 1u);      // RNE
    return (unsigned short)(u >> 16);
}
__device__ __forceinline__ float sigmoidf_(float x) {
    return 1.0f / (1.0f + __expf(-x));
}
__device__ __forceinline__ float tanhf_(float x) {
    return 2.0f / (1.0f + __expf(-2.0f * x)) - 1.0f;   // inf-safe at both tails
}

__global__ __launch_bounds__(256, 1)
void stn_lstm_kernel(const float* __restrict__ x,
                     const float* __restrict__ W_ih,
                     const float* __restrict__ W_hh,
                     const float* __restrict__ b_ih,
                     const float* __restrict__ b_hh,
                     float* __restrict__ out,
                     unsigned* __restrict__ flags,   // [NG][64] generation flags
                     u64* __restrict__ hbuf)         // [2][NG][64 rows][32 u64] payload
{
    __shared__ float gates_p[2][2][RR][17];   // [parity][kh][gaterow][batch+pad]

    const int tid = threadIdx.x;
    const int bid = blockIdx.x;
    const int g   = bid & 3;
    const int u   = bid >> 2;
    const int bg0 = g * GB;

    const int lane = tid & 63;
    const int wv   = tid >> 6;
    const int nt   = wv >> 1;                 // n-tile (16 gate rows)
    const int kh   = wv & 1;                  // K half (chunks kh*36 .. kh*36+35)
    const int quad = lane >> 4;
    const int m16  = lane & 15;
    const int rr   = nt * 16 + m16;

    // ---- W fragments + bias into registers (once; chunk c==MFMA K-window slot) ----
    const int Rg = ((rr >> 3) << 9) + u * 8 + (rr & 7);
    short8 wreg[9];
    #pragma unroll
    for (int kt = 0; kt < 9; ++kt) {
        const int c = kh * 36 + kt * 4 + quad;           // 0..71
        const float* src = (c < 64) ? (W_hh + (size_t)Rg * Hs + c * 8)
                                    : (W_ih + (size_t)Rg * INs + (c - 64) * 8);
        short8 w;
        #pragma unroll
        for (int e = 0; e < 8; ++e) w[e] = (short)f2bf(src[e]);
        wreg[kt] = w;
    }
    const float bv = (kh == 0) ? (b_ih[Rg] + b_hh[Rg]) : 0.0f;  // bias folded into acc init

    // per-lane x stream (kh==1 waves consume chunks 64..71)
    const float* xp = x + (size_t)(bg0 + m16) * Tlen * INs;

    // pointwise thread state (wave 0 only: 16 batches x 4 unit-pairs)
    const int eb = tid >> 2;                  // batch 0..15 (valid tid<64)
    const int jp = tid & 3;                   // unit-pair 0..3
    float h0s = 0.f, c0s = 0.f, h1s = 0.f, c1s = 0.f;
    float* op = out + (size_t)(bg0 + eb) * Tlen * Hs + u * 8 + 2 * jp;

    // this wave only consumes rows published by WGs [kh*36 .. ) — poll just those
    const bool pollmask = (kh == 0) ? (lane < 36) : (lane >= 36);

    for (int t = 0; t < Tlen; ++t) {
        const int par = t & 1;

        // ---- x prefetch (issued before the poll: HBM latency hides under it) ----
        floatx4 xa, xb, xc, xd;
        if (kh == 1) {
            xa = *(const floatx4*)(xp + quad * 8);
            xb = *(const floatx4*)(xp + quad * 8 + 4);
            xc = *(const floatx4*)(xp + 32 + quad * 8);
            xd = *(const floatx4*)(xp + 32 + quad * 8 + 4);
            xp += INs;
        }

        // ---- wave-parallel flag poll (monotonic generations, no RMW) ----
        if (t > 0) {
            const unsigned tgt = (unsigned)t;
            unsigned f;
            do {
                f = __hip_atomic_load(&flags[g * 64 + lane], __ATOMIC_RELAXED,
                                      __HIP_MEMORY_SCOPE_AGENT);
            } while (__any(pollmask && (f < tgt)));
        }
        __builtin_amdgcn_sched_barrier(0);    // keep payload loads below the poll

        // ---- A-fragments straight from LLC payload into registers ----
        u64 p0[9], p1[9];
        {
            const size_t rb = ((size_t)par * NG + g) * 64;
            #pragma unroll
            for (int kt = 0; kt < 9; ++kt) {
                if (kt < 7 || kh == 0) {      // kh==1, kt>=7 are x chunks
                    const int c = kh * 36 + kt * 4 + quad;
                    const u64* q = hbuf + (rb + c) * 32 + m16 * 2;
                    p0[kt] = __hip_atomic_load(q,     __ATOMIC_RELAXED, __HIP_MEMORY_SCOPE_SYSTEM);
                    p1[kt] = __hip_atomic_load(q + 1, __ATOMIC_RELAXED, __HIP_MEMORY_SCOPE_SYSTEM);
                }
            }
        }

        // ---- MFMA over this wave's 9 K-windows (two interleaved acc chains) ----
        floatx4 acc0 = {bv, bv, bv, bv};
        floatx4 acc1 = {0.f, 0.f, 0.f, 0.f};
        #pragma unroll
        for (int kt = 0; kt < 9; ++kt) {
            short8 af;
            if (kt >= 7 && kh == 1) {
                const floatx4 lo = (kt == 7) ? xa : xc;
                const floatx4 hi = (kt == 7) ? xb : xd;
                af[0] = (short)f2bf(lo[0]); af[1] = (short)f2bf(lo[1]);
                af[2] = (short)f2bf(lo[2]); af[3] = (short)f2bf(lo[3]);
                af[4] = (short)f2bf(hi[0]); af[5] = (short)f2bf(hi[1]);
                af[6] = (short)f2bf(hi[2]); af[7] = (short)f2bf(hi[3]);
            } else {
                union { u64 q[2]; short8 s; } cv;
                cv.q[0] = p0[kt]; cv.q[1] = p1[kt];
                af = cv.s;
            }
            if (kt & 1) acc1 = __builtin_amdgcn_mfma_f32_16x16x32_bf16(af, wreg[kt], acc1, 0, 0, 0);
            else        acc0 = __builtin_amdgcn_mfma_f32_16x16x32_bf16(af, wreg[kt], acc0, 0, 0, 0);
        }
        const floatx4 acc = acc0 + acc1;
        #pragma unroll
        for (int r2 = 0; r2 < 4; ++r2)
            gates_p[par][kh][rr][quad * 4 + r2] = acc[r2];  // D: row(batch)=quad*4+r2, col=m16

        __syncthreads();   // the ONE barrier per step (gates handoff)

        // ---- pointwise + publish: wave 0, 2 adjacent units per thread ----
        if (tid < 64) {
            const int e0 = 2 * jp, e1 = e0 + 1;
            const float gi0 = gates_p[par][0][e0][eb]      + gates_p[par][1][e0][eb];
            const float gf0 = gates_p[par][0][8 + e0][eb]  + gates_p[par][1][8 + e0][eb];
            const float gg0 = gates_p[par][0][16 + e0][eb] + gates_p[par][1][16 + e0][eb];
            const float go0 = gates_p[par][0][24 + e0][eb] + gates_p[par][1][24 + e0][eb];
            const float gi1 = gates_p[par][0][e1][eb]      + gates_p[par][1][e1][eb];
            const float gf1 = gates_p[par][0][8 + e1][eb]  + gates_p[par][1][8 + e1][eb];
            const float gg1 = gates_p[par][0][16 + e1][eb] + gates_p[par][1][16 + e1][eb];
            const float go1 = gates_p[par][0][24 + e1][eb] + gates_p[par][1][24 + e1][eb];

            const float cn0 = sigmoidf_(gf0) * c0s + sigmoidf_(gi0) * tanhf_(gg0);
            const float hn0 = sigmoidf_(go0) * tanhf_(cn0);
            const float cn1 = sigmoidf_(gf1) * c1s + sigmoidf_(gi1) * tanhf_(gg1);
            const float hn1 = sigmoidf_(go1) * tanhf_(cn1);
            const float h20 = 0.5f * (h0s + hn0), c20 = 0.5f * (c0s + cn0);
            const float h21 = 0.5f * (h1s + hn1), c21 = 0.5f * (c1s + cn1);
            h0s = h20; c0s = c20; h1s = h21; c1s = c21;

            // payload word (units 2jp,2jp+1 of batch eb) -> LLC, then flag
            const unsigned w = (unsigned)f2bf(h20) | ((unsigned)f2bf(h21) << 16);
            const size_t widx = (((size_t)(par ^ 1) * NG + g) * 64 + u) * 64 + eb * 4 + jp;
            __hip_atomic_store((unsigned*)hbuf + widx, w, __ATOMIC_RELAXED,
                               __HIP_MEMORY_SCOPE_SYSTEM);
            __builtin_amdgcn_sched_barrier(0);
            __builtin_amdgcn_s_waitcnt(0x0f70);   // vmcnt(0): payload acked at LLC
            __builtin_amdgcn_sched_barrier(0);
            if (tid == 0)
                __hip_atomic_store(&flags[g * 64 + u], (unsigned)(t + 1),
                                   __ATOMIC_RELAXED, __HIP_MEMORY_SCOPE_AGENT);
            // out write AFTER the flag store (off the critical path)
            floatx2 ov; ov[0] = h20; ov[1] = h21;
            __builtin_nontemporal_store(ov, (floatx2*)op);
            op += Hs;
        }
    }

    // ---- final [hT, cT] ----
    if (tid < 64) {
        const size_t base = (size_t)Bsz * Tlen * Hs;
        float* fp = out + base + (size_t)(bg0 + eb) * 1024 + u * 8 + 2 * jp;
        floatx2 hv; hv[0] = h0s; hv[1] = h1s;
        floatx2 cv; cv[0] = c0s; cv[1] = c1s;
        *(floatx2*)fp = hv;
        *(floatx2*)(fp + 512) = cv;
    }
}

extern "C" void kernel_launch(void* const* d_in, const int* in_sizes, int n_in,
                              void* d_out, int out_size, void* d_ws, size_t ws_size,
                              hipStream_t stream) {
    (void)in_sizes; (void)n_in; (void)out_size; (void)ws_size;
    const float* x    = (const float*)d_in[0];
    const float* W_ih = (const float*)d_in[1];
    const float* W_hh = (const float*)d_in[2];
    const float* b_ih = (const float*)d_in[3];
    const float* b_hh = (const float*)d_in[4];
    float* out = (float*)d_out;
    unsigned* flags = (unsigned*)d_ws;                    // 1 KB: [NG][64] generations
    u64* hbuf = (u64*)((char*)d_ws + 1024);               // 2*4*64*256 B = 128 KB payload
    // zero flags + parity-0 payload (h0 = 0) each launch/replay
    hipMemsetAsync(d_ws, 0, 1024 + 65536, stream);
    hipLaunchKernelGGL(stn_lstm_kernel, dim3(256), dim3(256), 0, stream,
                       x, W_ih, W_hh, b_ih, b_hh, out, flags, hbuf);
}